// Round 1
// 268.129 us; speedup vs baseline: 1.0073x; 1.0073x over previous
//
#include <hip/hip_runtime.h>
#include <math.h>

// Problem constants (match reference file).
#define BATCH 256
#define VOCAB 128000
#define HIST  2048
#define EPS_T 1e-5f

// --- fused scan ---
#define SEGS 25
#define SEG_ELEMS (VOCAB / SEGS)       // 5120 elements per segment
#define SEG_VEC   (SEG_ELEMS / 4)      // 1280 float4s
#define SEG_WORDS (SEG_ELEMS / 32)     // 160 mask words per segment
#define BBLOCK 256
#define BWAVES (BBLOCK / 64)

// Order-preserving f32 -> u32 transform (no NaNs in this problem).
// a < b  <=>  fkey(a) < fkey(b); distinct bit patterns stay distinct.
__device__ __forceinline__ unsigned fkey(float f) {
    unsigned b = __float_as_uint(f);
    return (b & 0x80000000u) ? ~b : (b | 0x80000000u);
}

__device__ __forceinline__ void upd(float s, int idx, float& best, int& besti) {
    if (s > best || (s == best && idx < besti)) { best = s; besti = idx; }
}

__device__ __forceinline__ void body4(float4 l, unsigned w, int sh, float pen,
                                      int idx0, float& best, int& besti) {
    float e[4] = {l.x, l.y, l.z, l.w};
    #pragma unroll
    for (int j = 0; j < 4; j++) {
        float present = (float)((w >> (sh + j)) & 1u);
        float p = e[j] - pen * present;           // exact: present in {0,1}
        upd(p, idx0 + j, best, besti);
    }
}

__device__ __forceinline__ void body4s(float4 l, float4 g, unsigned w, int sh,
                                       float pen, float temp,
                                       int idx0, float& best, int& besti) {
    float e[4]  = {l.x, l.y, l.z, l.w};
    float gv[4] = {g.x, g.y, g.z, g.w};
    #pragma unroll
    for (int j = 0; j < 4; j++) {
        float present = (float)((w >> (sh + j)) & 1u);
        float p = e[j] - pen * present;
        float s = p / temp + gv[j];               // reference op order, IEEE div
        upd(s, idx0 + j, best, besti);
    }
}

__device__ __forceinline__ void setbit(int t, int segBase, unsigned* smask) {
    unsigned u = (unsigned)(t - segBase);
    if (u < (unsigned)SEG_ELEMS)
        atomicOr(&smask[u >> 5], 1u << (u & 31));
}

// One block per (row, segment). Builds the 160-word presence mask for its
// own segment in LDS from the row's 2048 history tokens (8 KB, L2-resident
// across the 25 blocks of a row) -- no separate mask kernel, no 8 MB gmask
// round-trip. Result folded into a per-row u64 atomicMax key.
__global__ __launch_bounds__(BBLOCK, 1) void fused_scan(
    const float* __restrict__ logits,        // [B, V]
    const float* __restrict__ gumbel,        // [B, V]
    const int*   __restrict__ token_ids,     // [B, L]
    const float* __restrict__ penalties,     // [B]
    const float* __restrict__ temps,         // [B]
    unsigned long long* __restrict__ keys)   // [B] packed (fkey(val)<<32)|~idx
{
    __shared__ unsigned smask[SEG_WORDS];
    __shared__ float wval[BWAVES];
    __shared__ int   widx[BWAVES];

    const int blk = blockIdx.x;
    const int b   = blk / SEGS;
    const int seg = blk - b * SEGS;
    const int tid = threadIdx.x;

    const float pen    = penalties[b];
    const float temp   = temps[b];
    const bool  greedy = (temp < EPS_T);

    const int segBase = seg * SEG_ELEMS;

    // zero the segment mask (160 < 256 threads)
    if (tid < SEG_WORDS) smask[tid] = 0u;

    // token loads first: their consumers (LDS atomics) wait vmcnt(N) with the
    // logits/gumbel burst still outstanding behind them.
    const int4* rt = (const int4*)(token_ids + (size_t)b * HIST);
    int4 ta = rt[tid];
    int4 tb = rt[tid + BBLOCK];
    __builtin_amdgcn_sched_barrier(0);

    const float4* lg = (const float4*)(logits + (size_t)b * VOCAB) + seg * SEG_VEC;
    const float4* gm = (const float4*)(gumbel + (size_t)b * VOCAB) + seg * SEG_VEC;

    float best  = -INFINITY;
    int   besti = 0x7fffffff;
    const int sh    = (tid * 4) & 31;          // uniform across k (stride 1024 elems)
    const int abs0  = segBase + tid * 4;
    const int wbase = tid >> 3;                // mask word idx, stride 32 per k

    if (greedy) {
        // full burst: 5 float4 issued before ANY consumption
        float4 l0 = lg[tid];
        float4 l1 = lg[tid + 1 * BBLOCK];
        float4 l2 = lg[tid + 2 * BBLOCK];
        float4 l3 = lg[tid + 3 * BBLOCK];
        float4 l4 = lg[tid + 4 * BBLOCK];
        __builtin_amdgcn_sched_barrier(0);     // loads stay hoisted

        __syncthreads();                       // zeros visible (drains vmcnt too)
        setbit(ta.x, segBase, smask); setbit(ta.y, segBase, smask);
        setbit(ta.z, segBase, smask); setbit(ta.w, segBase, smask);
        setbit(tb.x, segBase, smask); setbit(tb.y, segBase, smask);
        setbit(tb.z, segBase, smask); setbit(tb.w, segBase, smask);
        __syncthreads();                       // mask complete

        unsigned w0 = smask[wbase];
        unsigned w1 = smask[wbase + 32];
        unsigned w2 = smask[wbase + 64];
        unsigned w3 = smask[wbase + 96];
        unsigned w4 = smask[wbase + 128];
        body4(l0, w0, sh, pen, abs0 + 0 * BBLOCK * 4, best, besti);
        body4(l1, w1, sh, pen, abs0 + 1 * BBLOCK * 4, best, besti);
        body4(l2, w2, sh, pen, abs0 + 2 * BBLOCK * 4, best, besti);
        body4(l3, w3, sh, pen, abs0 + 3 * BBLOCK * 4, best, besti);
        body4(l4, w4, sh, pen, abs0 + 4 * BBLOCK * 4, best, besti);
    } else {
        float4 l0 = lg[tid];
        float4 l1 = lg[tid + 1 * BBLOCK];
        float4 l2 = lg[tid + 2 * BBLOCK];
        float4 l3 = lg[tid + 3 * BBLOCK];
        float4 l4 = lg[tid + 4 * BBLOCK];
        float4 g0 = gm[tid];
        float4 g1 = gm[tid + 1 * BBLOCK];
        float4 g2 = gm[tid + 2 * BBLOCK];
        float4 g3 = gm[tid + 3 * BBLOCK];
        float4 g4 = gm[tid + 4 * BBLOCK];
        __builtin_amdgcn_sched_barrier(0);     // loads stay hoisted

        __syncthreads();                       // zeros visible (drains vmcnt too)
        setbit(ta.x, segBase, smask); setbit(ta.y, segBase, smask);
        setbit(ta.z, segBase, smask); setbit(ta.w, segBase, smask);
        setbit(tb.x, segBase, smask); setbit(tb.y, segBase, smask);
        setbit(tb.z, segBase, smask); setbit(tb.w, segBase, smask);
        __syncthreads();                       // mask complete

        unsigned w0 = smask[wbase];
        unsigned w1 = smask[wbase + 32];
        unsigned w2 = smask[wbase + 64];
        unsigned w3 = smask[wbase + 96];
        unsigned w4 = smask[wbase + 128];
        body4s(l0, g0, w0, sh, pen, temp, abs0 + 0 * BBLOCK * 4, best, besti);
        body4s(l1, g1, w1, sh, pen, temp, abs0 + 1 * BBLOCK * 4, best, besti);
        body4s(l2, g2, w2, sh, pen, temp, abs0 + 2 * BBLOCK * 4, best, besti);
        body4s(l3, g3, w3, sh, pen, temp, abs0 + 3 * BBLOCK * 4, best, besti);
        body4s(l4, g4, w4, sh, pen, temp, abs0 + 4 * BBLOCK * 4, best, besti);
    }

    // wave argmax reduction (64 lanes), first-index tie-break
    #pragma unroll
    for (int off = 32; off > 0; off >>= 1) {
        float ov = __shfl_down(best, off, 64);
        int   oi = __shfl_down(besti, off, 64);
        if (ov > best || (ov == best && oi < besti)) { best = ov; besti = oi; }
    }
    const int wave = tid >> 6, lane = tid & 63;
    if (lane == 0) { wval[wave] = best; widx[wave] = besti; }
    __syncthreads();

    if (tid == 0) {
        #pragma unroll
        for (int wv = 1; wv < BWAVES; wv++) {
            if (wval[wv] > best || (wval[wv] == best && widx[wv] < besti)) {
                best = wval[wv]; besti = widx[wv];
            }
        }
        // pack: bigger value wins; equal value -> max(~idx) = min idx (numpy tie-break)
        unsigned long long key =
            ((unsigned long long)fkey(best) << 32) | (unsigned)(~besti);
        atomicMax(keys + b, key);              // device-scope, 25 updates/row
    }
}

__global__ void decode_kernel(const unsigned long long* __restrict__ keys,
                              int* __restrict__ out)
{
    const int b = threadIdx.x;                 // 256 threads, one per row
    out[b] = (int)(~(unsigned)keys[b]);
}

extern "C" void kernel_launch(void* const* d_in, const int* in_sizes, int n_in,
                              void* d_out, int out_size, void* d_ws, size_t ws_size,
                              hipStream_t stream) {
    const float* logits    = (const float*)d_in[0];
    const int*   token_ids = (const int*)d_in[1];
    const float* penalties = (const float*)d_in[2];
    const float* temps     = (const float*)d_in[3];
    const float* gumbel    = (const float*)d_in[4];
    int* out = (int*)d_out;

    unsigned long long* keys = (unsigned long long*)d_ws;   // 2 KB

    // keys = 0 is below every real packed key (fkey >= 0x007FFFFF for all
    // finite floats incl. -FLT_MAX), so memset-0 is a valid -inf init.
    hipMemsetAsync(keys, 0, BATCH * sizeof(unsigned long long), stream);

    fused_scan<<<BATCH * SEGS, BBLOCK, 0, stream>>>(logits, gumbel, token_ids,
                                                    penalties, temps, keys);
    decode_kernel<<<1, BATCH, 0, stream>>>(keys, out);
}